// Round 2
// baseline (624.131 us; speedup 1.0000x reference)
//
#include <hip/hip_runtime.h>
#include <hip/hip_bf16.h>
#include <cstdint>

#define NODES  65536
#define CH     128
#define NGRAPH 1024
#define PGRAPH 64
#define FCO    65536

// ---------------- graph preprocessing ----------------

__global__ void k_degree(const int* __restrict__ dst, int* __restrict__ deg, int E){
  int e = blockIdx.x*256 + threadIdx.x;
  if (e < E) atomicAdd(&deg[dst[e]], 1);
}

__global__ void k_dinv(const int* __restrict__ deg, float* __restrict__ dinv){
  int i = blockIdx.x*256 + threadIdx.x;
  // self-loop adds 1 -> deg+1 >= 1 always
  dinv[i] = 1.0f / sqrtf((float)(deg[i] + 1));
}

// exclusive scan of deg[65536] -> cstart, 3 small kernels
__global__ void k_scan1(const int* __restrict__ deg, int* __restrict__ excl,
                        int* __restrict__ bsums){
  __shared__ int tmp[256];
  const int t = threadIdx.x;
  const int gid = blockIdx.x*256 + t;
  const int v = deg[gid];
  tmp[t] = v;
  __syncthreads();
  #pragma unroll
  for (int off = 1; off < 256; off <<= 1){
    int x = (t >= off) ? tmp[t-off] : 0;
    __syncthreads();
    tmp[t] += x;
    __syncthreads();
  }
  excl[gid] = tmp[t] - v;
  if (t == 255) bsums[blockIdx.x] = tmp[255];
}

__global__ void k_scan2(int* __restrict__ bsums){
  __shared__ int tmp[256];
  const int t = threadIdx.x;
  const int v = bsums[t];
  tmp[t] = v;
  __syncthreads();
  #pragma unroll
  for (int off = 1; off < 256; off <<= 1){
    int x = (t >= off) ? tmp[t-off] : 0;
    __syncthreads();
    tmp[t] += x;
    __syncthreads();
  }
  bsums[t] = tmp[t] - v;   // exclusive
}

__global__ void k_scan3(int* __restrict__ cstart, const int* __restrict__ bsums, int E){
  const int gid = blockIdx.x*256 + threadIdx.x;
  cstart[gid] += bsums[blockIdx.x];
  if (gid == 0) cstart[NODES] = E;
}

__global__ void k_scatter(const int* __restrict__ src, const int* __restrict__ dst,
                          const int* __restrict__ cstart, int* __restrict__ cursor,
                          int* __restrict__ ssrc, int E){
  int e = blockIdx.x*256 + threadIdx.x;
  if (e >= E) return;
  const int d = dst[e];
  const int p = cstart[d] + atomicAdd(&cursor[d], 1);
  ssrc[p] = src[e];
}

// ---------------- GEMM: C[n x 128] = act(A)[n x 128] @ W[128 x 128] ----------------
// ACT==1: A-element -> relu(a + bias[k]) applied on the fly (fuses previous layer's
// bias+relu into this GEMM's read).
template<int ACT>
__global__ __launch_bounds__(256)
void k_gemm128(const float* __restrict__ A, const float* __restrict__ W,
               const float* __restrict__ bias, float* __restrict__ Cout){
  __shared__ float As[128][36];    // 128 rows x 32 k, pad 36 (bank-spread, 16B-aligned rows)
  __shared__ float Ws[32][160];    // 32 k x 128 cols, each 32-col group padded to 40
  const int t  = threadIdx.x;
  const int r0 = blockIdx.x * 128;
  const int q  = t & 3;            // column group of 32
  const int rp = t >> 2;           // 0..63 -> rows rp and rp+64

  float acc0[32], acc1[32];
  #pragma unroll
  for (int j = 0; j < 32; ++j){ acc0[j] = 0.f; acc1[j] = 0.f; }

  for (int kc = 0; kc < 128; kc += 32){
    { // stage A tile
      const int row = t >> 1, u = t & 1;
      const float* ap = A + (size_t)(r0+row)*CH + kc + u*16;
      float* asp = &As[row][u*16];
      #pragma unroll
      for (int i = 0; i < 4; ++i){
        float4 v = *(const float4*)(ap + 4*i);
        if (ACT){
          const float4 bb = *(const float4*)(bias + kc + u*16 + 4*i);
          v.x = fmaxf(v.x+bb.x, 0.f); v.y = fmaxf(v.y+bb.y, 0.f);
          v.z = fmaxf(v.z+bb.z, 0.f); v.w = fmaxf(v.w+bb.w, 0.f);
        }
        *(float4*)(asp + 4*i) = v;
      }
    }
    { // stage W tile (32->40 group padding: phys col = (col/32)*40 + col%32)
      const int kk = t >> 3, u = t & 7;
      const float* wp = W + (size_t)(kc+kk)*CH + u*16;
      float* wsp = &Ws[kk][(u>>1)*40 + (u&1)*16];
      #pragma unroll
      for (int i = 0; i < 4; ++i)
        *(float4*)(wsp + 4*i) = *(const float4*)(wp + 4*i);
    }
    __syncthreads();

    #pragma unroll
    for (int kk4 = 0; kk4 < 8; ++kk4){
      const float4 a0 = *(const float4*)&As[rp][kk4*4];
      const float4 a1 = *(const float4*)&As[rp+64][kk4*4];
      const float a0f[4] = {a0.x, a0.y, a0.z, a0.w};
      const float a1f[4] = {a1.x, a1.y, a1.z, a1.w};
      #pragma unroll
      for (int kk = 0; kk < 4; ++kk){
        const float av0 = a0f[kk], av1 = a1f[kk];
        #pragma unroll
        for (int j4 = 0; j4 < 8; ++j4){
          const float4 w = *(const float4*)&Ws[kk4*4+kk][q*40 + j4*4];
          acc0[j4*4+0] = fmaf(av0, w.x, acc0[j4*4+0]);
          acc0[j4*4+1] = fmaf(av0, w.y, acc0[j4*4+1]);
          acc0[j4*4+2] = fmaf(av0, w.z, acc0[j4*4+2]);
          acc0[j4*4+3] = fmaf(av0, w.w, acc0[j4*4+3]);
          acc1[j4*4+0] = fmaf(av1, w.x, acc1[j4*4+0]);
          acc1[j4*4+1] = fmaf(av1, w.y, acc1[j4*4+1]);
          acc1[j4*4+2] = fmaf(av1, w.z, acc1[j4*4+2]);
          acc1[j4*4+3] = fmaf(av1, w.w, acc1[j4*4+3]);
        }
      }
    }
    __syncthreads();
  }

  float* c0 = Cout + (size_t)(r0+rp)*CH    + q*32;
  float* c1 = Cout + (size_t)(r0+rp+64)*CH + q*32;
  #pragma unroll
  for (int j4 = 0; j4 < 8; ++j4){
    *(float4*)(c0 + j4*4) = make_float4(acc0[j4*4], acc0[j4*4+1], acc0[j4*4+2], acc0[j4*4+3]);
    *(float4*)(c1 + j4*4) = make_float4(acc1[j4*4], acc1[j4*4+1], acc1[j4*4+2], acc1[j4*4+3]);
  }
}

// ---------------- CSR aggregation: out[i] = dinv[i]*(sum_e dinv[s]*hw[s] + dinv[i]*hw[i]) ----------------
__global__ void k_agg(const float* __restrict__ hw, const float* __restrict__ dinv,
                      const int* __restrict__ start, const int* __restrict__ srcs,
                      float* __restrict__ outp){
  const int i = blockIdx.x;
  const int c = threadIdx.x;            // 128 threads = 2 waves, 1 channel each
  const float di = dinv[i];
  float acc = di * hw[(size_t)i*CH + c];   // self-loop term (x di at the end -> di^2)
  int p = start[i];
  const int p1 = start[i+1];
  for (; p + 1 < p1; p += 2){
    const int s0 = srcs[p], s1 = srcs[p+1];
    const float w0 = dinv[s0], w1 = dinv[s1];
    acc += w0 * hw[(size_t)s0*CH + c];
    acc += w1 * hw[(size_t)s1*CH + c];
  }
  if (p < p1){
    const int s = srcs[p];
    acc += dinv[s] * hw[(size_t)s*CH + c];
  }
  outp[(size_t)i*CH + c] = di * acc;
}

// ---------------- pool: pooled[g] = mean_i relu(h[g*64+i] + b2) ----------------
__global__ void k_pool(const float* __restrict__ h, const float* __restrict__ b2,
                       float* __restrict__ pooled){
  const int g = blockIdx.x, c = threadIdx.x;
  const float bb = b2[c];
  float acc = 0.f;
  const float* hp = h + (size_t)g*PGRAPH*CH + c;
  #pragma unroll 4
  for (int i = 0; i < PGRAPH; ++i) acc += fmaxf(hp[i*CH] + bb, 0.f);
  pooled[g*CH + c] = acc * (1.0f/64.0f);
}

// ---------------- FC: out[1024 x 65536] = pooled[1024 x 128] @ Wfc + bfc ----------------
// block: 64 graphs x 512 cols (256 thr x 2 cols). pooled tile in LDS, broadcast reads.
__global__ __launch_bounds__(256)
void k_fc(const float* __restrict__ pooled, const float* __restrict__ Wfc,
          const float* __restrict__ bfc, float* __restrict__ out){
  __shared__ float ps[64][128];   // 32 KB
  const int t    = threadIdx.x;
  const int g0   = blockIdx.y * 64;
  const int colA = blockIdx.x*512 + t;
  const int colB = colA + 256;

  {
    float4* d = (float4*)&ps[0][0];
    const float4* s = (const float4*)(pooled + (size_t)g0*CH);
    for (int i = t; i < 2048; i += 256) d[i] = s[i];
  }
  __syncthreads();

  float accA[64], accB[64];
  #pragma unroll
  for (int g = 0; g < 64; ++g){ accA[g] = 0.f; accB[g] = 0.f; }

  for (int k4 = 0; k4 < 32; ++k4){
    const float* wp = Wfc + (size_t)(k4*4)*FCO;
    const float wa0 = wp[colA],         wa1 = wp[FCO + colA];
    const float wa2 = wp[2*FCO + colA], wa3 = wp[3*FCO + colA];
    const float wb0 = wp[colB],         wb1 = wp[FCO + colB];
    const float wb2 = wp[2*FCO + colB], wb3 = wp[3*FCO + colB];
    #pragma unroll
    for (int g = 0; g < 64; ++g){
      const float4 p = *(const float4*)&ps[g][k4*4];
      accA[g] = fmaf(p.x, wa0, accA[g]); accA[g] = fmaf(p.y, wa1, accA[g]);
      accA[g] = fmaf(p.z, wa2, accA[g]); accA[g] = fmaf(p.w, wa3, accA[g]);
      accB[g] = fmaf(p.x, wb0, accB[g]); accB[g] = fmaf(p.y, wb1, accB[g]);
      accB[g] = fmaf(p.z, wb2, accB[g]); accB[g] = fmaf(p.w, wb3, accB[g]);
    }
  }

  const float ba = bfc[colA], bb = bfc[colB];
  #pragma unroll
  for (int g = 0; g < 64; ++g){
    out[(size_t)(g0+g)*FCO + colA] = accA[g] + ba;
    out[(size_t)(g0+g)*FCO + colB] = accB[g] + bb;
  }
}

// ---------------- launch ----------------

extern "C" void kernel_launch(void* const* d_in, const int* in_sizes, int n_in,
                              void* d_out, int out_size, void* d_ws, size_t ws_size,
                              hipStream_t stream){
  const float* x   = (const float*)d_in[0];
  const int*   ei  = (const int*)d_in[1];   // [2, E] int32 (jax x64 off)
  // d_in[2] (batch) unused: graph id = node/64 by construction
  const float* W1  = (const float*)d_in[3];
  const float* b1  = (const float*)d_in[4];
  const float* W2  = (const float*)d_in[5];
  const float* b2  = (const float*)d_in[6];
  const float* Wfc = (const float*)d_in[7];
  const float* bfc = (const float*)d_in[8];
  float* out = (float*)d_out;
  const int E = in_sizes[1] / 2;

  // workspace layout (~73 MB)
  float* bufA   = (float*)d_ws;                      // 33.5 MB
  float* bufB   = bufA + (size_t)NODES*CH;           // 33.5 MB
  float* dinv   = bufB + (size_t)NODES*CH;           // 256 KB
  int*   deg    = (int*)(dinv + NODES);              // 256 KB
  int*   cstart = deg + NODES;                       // NODES+1 (reserve +256)
  int*   cursor = cstart + NODES + 256;              // 256 KB
  int*   bsums  = cursor + NODES;                    // 1 KB
  int*   ssrc   = bsums + 256;                       // 4 MB
  float* pooled = (float*)(ssrc + E);                // 512 KB

  const int* esrc = ei;
  const int* edst = ei + E;

  hipMemsetAsync(deg,    0, NODES*sizeof(int), stream);
  hipMemsetAsync(cursor, 0, NODES*sizeof(int), stream);

  k_degree <<<(E+255)/256, 256, 0, stream>>>(edst, deg, E);
  k_dinv   <<<NODES/256,   256, 0, stream>>>(deg, dinv);
  k_scan1  <<<NODES/256,   256, 0, stream>>>(deg, cstart, bsums);
  k_scan2  <<<1,           256, 0, stream>>>(bsums);
  k_scan3  <<<NODES/256,   256, 0, stream>>>(cstart, bsums, E);
  k_scatter<<<(E+255)/256, 256, 0, stream>>>(esrc, edst, cstart, cursor, ssrc, E);

  k_gemm128<0><<<NODES/128, 256, 0, stream>>>(x,    W1, nullptr, bufA); // bufA = x@W1
  k_agg       <<<NODES, CH, 0, stream>>>(bufA, dinv, cstart, ssrc, bufB); // bufB = agg1
  k_gemm128<1><<<NODES/128, 256, 0, stream>>>(bufB, W2, b1,     bufA); // bufA = relu(agg1+b1)@W2
  k_agg       <<<NODES, CH, 0, stream>>>(bufA, dinv, cstart, ssrc, bufB); // bufB = agg2
  k_pool      <<<NGRAPH, CH, 0, stream>>>(bufB, b2, pooled);
  k_fc        <<<dim3(FCO/512, NGRAPH/64), 256, 0, stream>>>(pooled, Wfc, bfc, out);
}

// Round 3
// 602.017 us; speedup vs baseline: 1.0367x; 1.0367x over previous
//
#include <hip/hip_runtime.h>
#include <hip/hip_bf16.h>
#include <cstdint>

#define NODES  65536
#define CH     128
#define NGRAPH 1024
#define PGRAPH 64
#define FCO    65536

// ---------------- graph preprocessing ----------------

__global__ void k_degree(const int* __restrict__ dst, int* __restrict__ deg, int E){
  int e = blockIdx.x*256 + threadIdx.x;
  if (e < E) atomicAdd(&deg[dst[e]], 1);
}

__global__ void k_dinv(const int* __restrict__ deg, float* __restrict__ dinv){
  int i = blockIdx.x*256 + threadIdx.x;
  // self-loop adds 1 -> deg+1 >= 1 always
  dinv[i] = 1.0f / sqrtf((float)(deg[i] + 1));
}

// exclusive scan of deg[65536] -> cstart, 3 small kernels
__global__ void k_scan1(const int* __restrict__ deg, int* __restrict__ excl,
                        int* __restrict__ bsums){
  __shared__ int tmp[256];
  const int t = threadIdx.x;
  const int gid = blockIdx.x*256 + t;
  const int v = deg[gid];
  tmp[t] = v;
  __syncthreads();
  #pragma unroll
  for (int off = 1; off < 256; off <<= 1){
    int x = (t >= off) ? tmp[t-off] : 0;
    __syncthreads();
    tmp[t] += x;
    __syncthreads();
  }
  excl[gid] = tmp[t] - v;
  if (t == 255) bsums[blockIdx.x] = tmp[255];
}

__global__ void k_scan2(int* __restrict__ bsums){
  __shared__ int tmp[256];
  const int t = threadIdx.x;
  const int v = bsums[t];
  tmp[t] = v;
  __syncthreads();
  #pragma unroll
  for (int off = 1; off < 256; off <<= 1){
    int x = (t >= off) ? tmp[t-off] : 0;
    __syncthreads();
    tmp[t] += x;
    __syncthreads();
  }
  bsums[t] = tmp[t] - v;   // exclusive
}

__global__ void k_scan3(int* __restrict__ cstart, const int* __restrict__ bsums, int E){
  const int gid = blockIdx.x*256 + threadIdx.x;
  cstart[gid] += bsums[blockIdx.x];
  if (gid == 0) cstart[NODES] = E;
}

__global__ void k_scatter(const int* __restrict__ src, const int* __restrict__ dst,
                          const int* __restrict__ cstart, int* __restrict__ cursor,
                          int* __restrict__ ssrc, int E){
  int e = blockIdx.x*256 + threadIdx.x;
  if (e >= E) return;
  const int d = dst[e];
  const int p = cstart[d] + atomicAdd(&cursor[d], 1);
  ssrc[p] = src[e];
}

// ---------------- GEMM: C[n x 128] = act(A)[n x 128] @ W[128 x 128] ----------------
template<int ACT>
__global__ __launch_bounds__(256)
void k_gemm128(const float* __restrict__ A, const float* __restrict__ W,
               const float* __restrict__ bias, float* __restrict__ Cout){
  __shared__ float As[128][36];    // 128 rows x 32 k, pad 36
  __shared__ float Ws[32][160];    // 32 k x 128 cols, 32-col groups padded to 40
  const int t  = threadIdx.x;
  const int r0 = blockIdx.x * 128;
  const int q  = t & 3;            // column group of 32
  const int rp = t >> 2;           // 0..63 -> rows rp and rp+64

  float acc0[32], acc1[32];
  #pragma unroll
  for (int j = 0; j < 32; ++j){ acc0[j] = 0.f; acc1[j] = 0.f; }

  for (int kc = 0; kc < 128; kc += 32){
    { // stage A tile
      const int row = t >> 1, u = t & 1;
      const float* ap = A + (size_t)(r0+row)*CH + kc + u*16;
      float* asp = &As[row][u*16];
      #pragma unroll
      for (int i = 0; i < 4; ++i){
        float4 v = *(const float4*)(ap + 4*i);
        if (ACT){
          const float4 bb = *(const float4*)(bias + kc + u*16 + 4*i);
          v.x = fmaxf(v.x+bb.x, 0.f); v.y = fmaxf(v.y+bb.y, 0.f);
          v.z = fmaxf(v.z+bb.z, 0.f); v.w = fmaxf(v.w+bb.w, 0.f);
        }
        *(float4*)(asp + 4*i) = v;
      }
    }
    { // stage W tile (phys col = (col/32)*40 + col%32)
      const int kk = t >> 3, u = t & 7;
      const float* wp = W + (size_t)(kc+kk)*CH + u*16;
      float* wsp = &Ws[kk][(u>>1)*40 + (u&1)*16];
      #pragma unroll
      for (int i = 0; i < 4; ++i)
        *(float4*)(wsp + 4*i) = *(const float4*)(wp + 4*i);
    }
    __syncthreads();

    #pragma unroll
    for (int kk4 = 0; kk4 < 8; ++kk4){
      const float4 a0 = *(const float4*)&As[rp][kk4*4];
      const float4 a1 = *(const float4*)&As[rp+64][kk4*4];
      const float a0f[4] = {a0.x, a0.y, a0.z, a0.w};
      const float a1f[4] = {a1.x, a1.y, a1.z, a1.w};
      #pragma unroll
      for (int kk = 0; kk < 4; ++kk){
        const float av0 = a0f[kk], av1 = a1f[kk];
        #pragma unroll
        for (int j4 = 0; j4 < 8; ++j4){
          const float4 w = *(const float4*)&Ws[kk4*4+kk][q*40 + j4*4];
          acc0[j4*4+0] = fmaf(av0, w.x, acc0[j4*4+0]);
          acc0[j4*4+1] = fmaf(av0, w.y, acc0[j4*4+1]);
          acc0[j4*4+2] = fmaf(av0, w.z, acc0[j4*4+2]);
          acc0[j4*4+3] = fmaf(av0, w.w, acc0[j4*4+3]);
          acc1[j4*4+0] = fmaf(av1, w.x, acc1[j4*4+0]);
          acc1[j4*4+1] = fmaf(av1, w.y, acc1[j4*4+1]);
          acc1[j4*4+2] = fmaf(av1, w.z, acc1[j4*4+2]);
          acc1[j4*4+3] = fmaf(av1, w.w, acc1[j4*4+3]);
        }
      }
    }
    __syncthreads();
  }

  float* c0 = Cout + (size_t)(r0+rp)*CH    + q*32;
  float* c1 = Cout + (size_t)(r0+rp+64)*CH + q*32;
  #pragma unroll
  for (int j4 = 0; j4 < 8; ++j4){
    *(float4*)(c0 + j4*4) = make_float4(acc0[j4*4], acc0[j4*4+1], acc0[j4*4+2], acc0[j4*4+3]);
    *(float4*)(c1 + j4*4) = make_float4(acc1[j4*4], acc1[j4*4+1], acc1[j4*4+2], acc1[j4*4+3]);
  }
}

// ---------------- CSR aggregation ----------------
__global__ void k_agg(const float* __restrict__ hw, const float* __restrict__ dinv,
                      const int* __restrict__ start, const int* __restrict__ srcs,
                      float* __restrict__ outp){
  const int i = blockIdx.x;
  const int c = threadIdx.x;            // 128 threads = 2 waves, 1 channel each
  const float di = dinv[i];
  float acc = di * hw[(size_t)i*CH + c];   // self-loop term
  int p = start[i];
  const int p1 = start[i+1];
  for (; p + 1 < p1; p += 2){
    const int s0 = srcs[p], s1 = srcs[p+1];
    const float w0 = dinv[s0], w1 = dinv[s1];
    acc += w0 * hw[(size_t)s0*CH + c];
    acc += w1 * hw[(size_t)s1*CH + c];
  }
  if (p < p1){
    const int s = srcs[p];
    acc += dinv[s] * hw[(size_t)s*CH + c];
  }
  outp[(size_t)i*CH + c] = di * acc;
}

// ---------------- pool: pooledT[c][g] = mean_i relu(h[g*64+i][c] + b2[c]) ----------------
// TRANSPOSED output so k_fc can s_load contiguous per-k graph chunks.
__global__ void k_pool(const float* __restrict__ h, const float* __restrict__ b2,
                       float* __restrict__ pooledT){
  const int g = blockIdx.x, c = threadIdx.x;
  const float bb = b2[c];
  float acc = 0.f;
  const float* hp = h + (size_t)g*PGRAPH*CH + c;
  #pragma unroll 4
  for (int i = 0; i < PGRAPH; ++i) acc += fmaxf(hp[i*CH] + bb, 0.f);
  pooledT[(size_t)c*NGRAPH + g] = acc * (1.0f/64.0f);
}

// ---------------- FC: out[1024 x 65536] = pooled @ Wfc + bfc ----------------
// A-values are block-uniform -> feed via SGPR (s_load from pooledT), zero LDS.
// Thread: 2 adjacent cols (float2), 32 graphs. acc = 64 VGPR. grid (128, 32).
__global__ __launch_bounds__(256)
void k_fc(const float* __restrict__ pooledT, const float* __restrict__ Wfc,
          const float* __restrict__ bfc, float* __restrict__ out){
  const int t  = threadIdx.x;
  const int j  = blockIdx.x*512 + 2*t;
  const int g0 = blockIdx.y*32;

  float2 acc[32];
  #pragma unroll
  for (int g = 0; g < 32; ++g){ acc[g].x = 0.f; acc[g].y = 0.f; }

  const float* aT = pooledT + g0;          // row k at aT[k*1024 + g]
  const float* wp = Wfc + j;

  #pragma unroll 2
  for (int k = 0; k < 128; ++k){
    const float2 w = *(const float2*)(wp + (size_t)k*FCO);
    const float* ar = aT + (size_t)k*NGRAPH;   // uniform address -> s_load
    #pragma unroll
    for (int g = 0; g < 32; ++g){
      const float a = ar[g];                   // wave-uniform value (SGPR operand)
      acc[g].x = fmaf(a, w.x, acc[g].x);
      acc[g].y = fmaf(a, w.y, acc[g].y);
    }
  }

  const float2 bb = *(const float2*)(bfc + j);
  #pragma unroll
  for (int g = 0; g < 32; ++g){
    float2 v; v.x = acc[g].x + bb.x; v.y = acc[g].y + bb.y;
    *(float2*)(out + (size_t)(g0+g)*FCO + j) = v;
  }
}

// ---------------- launch ----------------

extern "C" void kernel_launch(void* const* d_in, const int* in_sizes, int n_in,
                              void* d_out, int out_size, void* d_ws, size_t ws_size,
                              hipStream_t stream){
  const float* x   = (const float*)d_in[0];
  const int*   ei  = (const int*)d_in[1];   // [2, E] int32 (jax x64 off)
  // d_in[2] (batch) unused: graph id = node/64 by construction
  const float* W1  = (const float*)d_in[3];
  const float* b1  = (const float*)d_in[4];
  const float* W2  = (const float*)d_in[5];
  const float* b2  = (const float*)d_in[6];
  const float* Wfc = (const float*)d_in[7];
  const float* bfc = (const float*)d_in[8];
  float* out = (float*)d_out;
  const int E = in_sizes[1] / 2;

  // workspace layout (~73 MB)
  float* bufA   = (float*)d_ws;                      // 33.5 MB
  float* bufB   = bufA + (size_t)NODES*CH;           // 33.5 MB
  float* dinv   = bufB + (size_t)NODES*CH;           // 256 KB
  int*   deg    = (int*)(dinv + NODES);              // 256 KB
  int*   cstart = deg + NODES;                       // NODES+1 (reserve +256)
  int*   cursor = cstart + NODES + 256;              // 256 KB
  int*   bsums  = cursor + NODES;                    // 1 KB
  int*   ssrc   = bsums + 256;                       // 4 MB
  float* pooledT= (float*)(ssrc + E);                // 512 KB  [128][1024]

  const int* esrc = ei;
  const int* edst = ei + E;

  hipMemsetAsync(deg,    0, NODES*sizeof(int), stream);
  hipMemsetAsync(cursor, 0, NODES*sizeof(int), stream);

  k_degree <<<(E+255)/256, 256, 0, stream>>>(edst, deg, E);
  k_dinv   <<<NODES/256,   256, 0, stream>>>(deg, dinv);
  k_scan1  <<<NODES/256,   256, 0, stream>>>(deg, cstart, bsums);
  k_scan2  <<<1,           256, 0, stream>>>(bsums);
  k_scan3  <<<NODES/256,   256, 0, stream>>>(cstart, bsums, E);
  k_scatter<<<(E+255)/256, 256, 0, stream>>>(esrc, edst, cstart, cursor, ssrc, E);

  k_gemm128<0><<<NODES/128, 256, 0, stream>>>(x,    W1, nullptr, bufA); // bufA = x@W1
  k_agg       <<<NODES, CH, 0, stream>>>(bufA, dinv, cstart, ssrc, bufB); // bufB = agg1
  k_gemm128<1><<<NODES/128, 256, 0, stream>>>(bufB, W2, b1,     bufA); // bufA = relu(agg1+b1)@W2
  k_agg       <<<NODES, CH, 0, stream>>>(bufA, dinv, cstart, ssrc, bufB); // bufB = agg2
  k_pool      <<<NGRAPH, CH, 0, stream>>>(bufB, b2, pooledT);
  k_fc        <<<dim3(FCO/512, NGRAPH/32), 256, 0, stream>>>(pooledT, Wfc, bfc, out);
}